// Round 2
// baseline (8427.883 us; speedup 1.0000x reference)
//
#include <hip/hip_runtime.h>

typedef _Float16 h2_t __attribute__((ext_vector_type(2)));

#define BATCH   262144
#define LATENT  100
#define HDIM    64
#define SEQ_LEN 30
#define DT      0.03f

__device__ __forceinline__ float sigm(float x) {
    return __fdividef(1.0f, 1.0f + __expf(-x));
}
__device__ __forceinline__ float tanh_f(float x) {
    float ax = fabsf(x);
    float e  = __expf(-2.0f * ax);
    return copysignf(__fdividef(1.0f - e, 1.0f + e), x);
}

// ws layout (float units):
//   [0, 1024)          Weff[256][4]   (W_ih @ W_emb folded)
//   [1024, 1280)       beff[256]      (W_ih@b_emb + b_ih + b_hh)
//   [1280, 1280+8192)  W_hh rows packed as half2: [256 rows][32 k-pairs]
__global__ void prep_kernel(const float* __restrict__ W_emb,
                            const float* __restrict__ b_emb,
                            const float* __restrict__ W_ih,
                            const float* __restrict__ b_ih,
                            const float* __restrict__ b_hh,
                            const float* __restrict__ W_hh,
                            float* __restrict__ ws) {
    int r = threadIdx.x;  // 0..255
    float a0 = 0.f, a1 = 0.f, a2 = 0.f, a3 = 0.f;
    float bb = b_ih[r] + b_hh[r];
    for (int k = 0; k < HDIM; ++k) {
        float w = W_ih[r * HDIM + k];
        a0 = fmaf(w, W_emb[k * 4 + 0], a0);
        a1 = fmaf(w, W_emb[k * 4 + 1], a1);
        a2 = fmaf(w, W_emb[k * 4 + 2], a2);
        a3 = fmaf(w, W_emb[k * 4 + 3], a3);
        bb = fmaf(w, b_emb[k], bb);
    }
    ws[r * 4 + 0] = a0; ws[r * 4 + 1] = a1;
    ws[r * 4 + 2] = a2; ws[r * 4 + 3] = a3;
    ws[1024 + r]  = bb;
    h2_t* w2 = (h2_t*)(ws + 1280);
    for (int kk = 0; kk < 32; ++kk) {
        h2_t v;
        v[0] = (_Float16)W_hh[r * HDIM + 2 * kk];
        v[1] = (_Float16)W_hh[r * HDIM + 2 * kk + 1];
        w2[r * 32 + kk] = v;
    }
}

__device__ __forceinline__ float fold4(const float* __restrict__ W, int row,
                                       float4 s, float a) {
    a = fmaf(W[row * 4 + 0], s.x, a);
    a = fmaf(W[row * 4 + 1], s.y, a);
    a = fmaf(W[row * 4 + 2], s.z, a);
    a = fmaf(W[row * 4 + 3], s.w, a);
    return a;
}

__launch_bounds__(256, 2)
__global__ void rollout_kernel(const float* __restrict__ z,
                               const float* __restrict__ init_state,
                               const float* __restrict__ W_ctrl,
                               const float* __restrict__ b_ctrl,
                               const float* __restrict__ W_init,
                               const float* __restrict__ b_init,
                               const float* __restrict__ ws,
                               float* __restrict__ out) {
    const int b = blockIdx.x * 256 + threadIdx.x;
    if (b >= BATCH) return;

    const float* __restrict__ Weff = ws;
    const float* __restrict__ beff = ws + 1024;
    const h2_t* __restrict__ w2    = (const h2_t*)(ws + 1280);

    // ---- c0 = h0 = z @ W_init.T + b_init (f32) ----
    float c[HDIM];
    #pragma unroll
    for (int j = 0; j < HDIM; ++j) c[j] = b_init[j];

    const float4* z4 = (const float4*)z;
    #pragma unroll 1
    for (int kk = 0; kk < LATENT / 4; ++kk) {
        float4 zv = z4[(size_t)b * (LATENT / 4) + kk];
        #pragma unroll
        for (int j = 0; j < HDIM; ++j) {
            c[j] = fmaf(zv.x, W_init[j * LATENT + kk * 4 + 0], c[j]);
            c[j] = fmaf(zv.y, W_init[j * LATENT + kk * 4 + 1], c[j]);
            c[j] = fmaf(zv.z, W_init[j * LATENT + kk * 4 + 2], c[j]);
            c[j] = fmaf(zv.w, W_init[j * LATENT + kk * 4 + 3], c[j]);
        }
    }

    // pack h0 into half2[32]
    h2_t h2[32];
    #pragma unroll
    for (int p = 0; p < 32; ++p) {
        h2_t v; v[0] = (_Float16)c[2 * p]; v[1] = (_Float16)c[2 * p + 1];
        h2[p] = v;
    }

    float4 s = ((const float4*)init_state)[b];
    float4* out4 = (float4*)out;
    const float bc0 = b_ctrl[0], bc1 = b_ctrl[1];

    #pragma unroll 1
    for (int t = 0; t < SEQ_LEN; ++t) {
        h2_t hn2[32];
        float ped = bc0, str = bc1;

// One j-pair: 8 packed-fma chains over 32 k-pairs, then activations.
// BASE is a literal -> all c[]/hn2[] indices are compile-time constants.
#define GATE_PAIR_CHUNK(BASE)                                                  \
        _Pragma("unroll")                                                      \
        for (int p = 0; p < 8; ++p) {                                          \
            const int j0 = (BASE) + 2 * p, j1 = j0 + 1;                        \
            const h2_t* Wi0 = w2 + (size_t)(      j0) * 32;                    \
            const h2_t* Wf0 = w2 + (size_t)( 64 + j0) * 32;                    \
            const h2_t* Wg0 = w2 + (size_t)(128 + j0) * 32;                    \
            const h2_t* Wo0 = w2 + (size_t)(192 + j0) * 32;                    \
            const h2_t* Wi1 = w2 + (size_t)(      j1) * 32;                    \
            const h2_t* Wf1 = w2 + (size_t)( 64 + j1) * 32;                    \
            const h2_t* Wg1 = w2 + (size_t)(128 + j1) * 32;                    \
            const h2_t* Wo1 = w2 + (size_t)(192 + j1) * 32;                    \
            h2_t vi0 = {0, 0}, vf0 = {0, 0}, vg0 = {0, 0}, vo0 = {0, 0};       \
            h2_t vi1 = {0, 0}, vf1 = {0, 0}, vg1 = {0, 0}, vo1 = {0, 0};       \
            _Pragma("unroll")                                                  \
            for (int kk = 0; kk < 32; ++kk) {                                  \
                h2_t hk = h2[kk];                                              \
                vi0 = __builtin_elementwise_fma(Wi0[kk], hk, vi0);             \
                vf0 = __builtin_elementwise_fma(Wf0[kk], hk, vf0);             \
                vg0 = __builtin_elementwise_fma(Wg0[kk], hk, vg0);             \
                vo0 = __builtin_elementwise_fma(Wo0[kk], hk, vo0);             \
                vi1 = __builtin_elementwise_fma(Wi1[kk], hk, vi1);             \
                vf1 = __builtin_elementwise_fma(Wf1[kk], hk, vf1);             \
                vg1 = __builtin_elementwise_fma(Wg1[kk], hk, vg1);             \
                vo1 = __builtin_elementwise_fma(Wo1[kk], hk, vo1);             \
            }                                                                  \
            float ai0 = fold4(Weff,       j0, s, beff[      j0]) + (float)vi0[0] + (float)vi0[1]; \
            float af0 = fold4(Weff,  64 + j0, s, beff[ 64 + j0]) + (float)vf0[0] + (float)vf0[1]; \
            float ag0 = fold4(Weff, 128 + j0, s, beff[128 + j0]) + (float)vg0[0] + (float)vg0[1]; \
            float ao0 = fold4(Weff, 192 + j0, s, beff[192 + j0]) + (float)vo0[0] + (float)vo0[1]; \
            float ai1 = fold4(Weff,       j1, s, beff[      j1]) + (float)vi1[0] + (float)vi1[1]; \
            float af1 = fold4(Weff,  64 + j1, s, beff[ 64 + j1]) + (float)vf1[0] + (float)vf1[1]; \
            float ag1 = fold4(Weff, 128 + j1, s, beff[128 + j1]) + (float)vg1[0] + (float)vg1[1]; \
            float ao1 = fold4(Weff, 192 + j1, s, beff[192 + j1]) + (float)vo1[0] + (float)vo1[1]; \
            float ig0 = sigm(ai0), fg0 = sigm(af0), gg0 = tanh_f(ag0), og0 = sigm(ao0); \
            float ig1 = sigm(ai1), fg1 = sigm(af1), gg1 = tanh_f(ag1), og1 = sigm(ao1); \
            float cj0 = fmaf(fg0, c[j0], ig0 * gg0); c[j0] = cj0;              \
            float cj1 = fmaf(fg1, c[j1], ig1 * gg1); c[j1] = cj1;              \
            float hn0 = og0 * tanh_f(cj0);                                     \
            float hn1 = og1 * tanh_f(cj1);                                     \
            ped = fmaf(W_ctrl[j0], hn0, ped);                                  \
            ped = fmaf(W_ctrl[j1], hn1, ped);                                  \
            str = fmaf(W_ctrl[64 + j0], hn0, str);                             \
            str = fmaf(W_ctrl[64 + j1], hn1, str);                             \
            h2_t hv; hv[0] = (_Float16)hn0; hv[1] = (_Float16)hn1;             \
            hn2[(BASE) / 2 + p] = hv;                                          \
        }

        GATE_PAIR_CHUNK(0)
        GATE_PAIR_CHUNK(16)
        GATE_PAIR_CHUNK(32)
        GATE_PAIR_CHUNK(48)
#undef GATE_PAIR_CHUNK

        #pragma unroll
        for (int p = 0; p < 32; ++p) h2[p] = hn2[p];

        // ---- plant (uses OLD s.z / s.w where required) ----
        float beta = fminf(0.5f, fmaxf(-0.5f, str));
        float v1   = fminf(10.0f, fmaxf(0.0f, fmaf(ped, DT, s.w)));
        float cpsi = __cosf(s.z);
        float spsi = __sinf(s.z);
        float tb   = __fdividef(__sinf(beta), __cosf(beta));
        float psid = fminf(1.57f, fmaxf(-1.57f, s.w * tb * 0.4f));
        s.x = fmaf(v1 * cpsi, DT, s.x);
        s.y = fmaf(v1 * spsi, DT, s.y);
        s.z = fmaf(psid, DT, s.z);
        s.w = v1;

        out4[(size_t)b * SEQ_LEN + t] = s;
    }
}

extern "C" void kernel_launch(void* const* d_in, const int* in_sizes, int n_in,
                              void* d_out, int out_size, void* d_ws, size_t ws_size,
                              hipStream_t stream) {
    const float* z          = (const float*)d_in[0];
    const float* init_state = (const float*)d_in[1];
    const float* W_emb      = (const float*)d_in[2];
    const float* b_emb      = (const float*)d_in[3];
    const float* W_ih       = (const float*)d_in[4];
    const float* W_hh       = (const float*)d_in[5];
    const float* b_ih       = (const float*)d_in[6];
    const float* b_hh       = (const float*)d_in[7];
    const float* W_ctrl     = (const float*)d_in[8];
    const float* b_ctrl     = (const float*)d_in[9];
    const float* W_init     = (const float*)d_in[10];
    const float* b_init     = (const float*)d_in[11];
    float* out = (float*)d_out;
    float* ws  = (float*)d_ws;

    prep_kernel<<<1, 256, 0, stream>>>(W_emb, b_emb, W_ih, b_ih, b_hh, W_hh, ws);
    rollout_kernel<<<BATCH / 256, 256, 0, stream>>>(
        z, init_state, W_ctrl, b_ctrl, W_init, b_init, ws, out);
}